// Round 17
// baseline (179.935 us; speedup 1.0000x reference)
//
#include <hip/hip_runtime.h>
#include <hip/hip_bf16.h>
#include <stdint.h>

typedef unsigned short u16;
typedef __attribute__((ext_vector_type(8))) short short8;   // 8 bf16 (4 VGPRs) MFMA A/B frag
typedef __attribute__((ext_vector_type(4))) float f32x4;    // MFMA C/D frag
typedef __attribute__((ext_vector_type(4))) unsigned short u16x4;

#define DEV static __device__ __forceinline__

// B=4, S=2048, D=1024, H=16, DK=64, DOUT=1024; M = B*S = 8192

DEV u16 f2bf(float f) {
  __hip_bfloat16 b = __float2bfloat16(f);
  return *(u16*)&b;
}

DEV void stage16(const u16* g, u16* l) {
  // async global->LDS, 16B per lane; LDS dest = wave-uniform base + lane*16
  __builtin_amdgcn_global_load_lds((const __attribute__((address_space(1))) void*)g,
                                   (__attribute__((address_space(3))) void*)l, 16, 0, 0);
}

// ---------------- conversions + LDS-mediated weight transposes ----------------
__global__ __launch_bounds__(256) void cvt_kernel(
    const float* __restrict__ x, const float* __restrict__ Wq,
    const float* __restrict__ Wk, const float* __restrict__ Wv,
    const float* __restrict__ Wo,
    u16* __restrict__ xb, u16* __restrict__ Wt, u16* __restrict__ Wot)
{
  const int bid = blockIdx.x, tid = threadIdx.x;
  if (bid < 4096) {                       // x: [8192][1024] f32 -> bf16, 8/thread
    int i = (bid*256 + tid) * 8;
    f32x4 v0 = *(const f32x4*)&x[i];
    f32x4 v1 = *(const f32x4*)&x[i + 4];
    short8 o;
    o[0]=f2bf(v0[0]); o[1]=f2bf(v0[1]); o[2]=f2bf(v0[2]); o[3]=f2bf(v0[3]);
    o[4]=f2bf(v1[0]); o[5]=f2bf(v1[1]); o[6]=f2bf(v1[2]); o[7]=f2bf(v1[3]);
    *(short8*)&xb[i] = o;
    return;
  }
  __shared__ u16 ldsT[64][72];            // padded: write-phase rows 16B-aligned
  const float* sp; size_t sstride; u16* dp;
  if (bid < 4864) {                       // Wq/Wk/Wv [H][D][DK] -> Wt[w][h*64+k][d]
    const int wb = bid - 4096;            // 768 blocks: (w, h, dblk)
    const int w = wb >> 8, rem = wb & 255;
    const int h = rem >> 4, db = rem & 15;
    const float* W = (w == 0) ? Wq : (w == 1) ? Wk : Wv;
    sp = W + (size_t)(h*1024 + db*64) * 64;
    sstride = 64;
    dp = Wt + (size_t)w*1048576 + (size_t)(h*64)*1024 + db*64;
  } else {                                // Wo [f][n] -> Wot[n][f]
    const int ob = bid - 4864;            // 256 blocks: (nb, fb)
    const int nb = ob >> 4, fb = ob & 15;
    sp = Wo + (size_t)(fb*64)*1024 + nb*64;
    sstride = 1024;
    dp = Wot + (size_t)(nb*64)*1024 + fb*64;
  }
  {   // coalesced read: 4 threads/row, 16 f32 each; scatter bf16 into ldsT[col][row]
    const int r = tid >> 2, c0 = (tid & 3) * 16;
    #pragma unroll
    for (int j = 0; j < 4; j++) {
      f32x4 v = *(const f32x4*)&sp[(size_t)r*sstride + c0 + j*4];
      #pragma unroll
      for (int i = 0; i < 4; i++) ldsT[c0 + j*4 + i][r] = f2bf(v[i]);
    }
  }
  __syncthreads();
  {   // coalesced write: 4 threads/row, 2x16B each
    const int k = tid >> 2, d0 = (tid & 3) * 16;
    short8 v0 = *(const short8*)&ldsT[k][d0];
    short8 v1 = *(const short8*)&ldsT[k][d0 + 8];
    *(short8*)&dp[(size_t)k*1024 + d0]     = v0;
    *(short8*)&dp[(size_t)k*1024 + d0 + 8] = v1;
  }
}

// ============ 256x128 2-phase-per-tile GEMM mainloop (BK=64, 8 waves 4Mx2N) ============
#define RDALL(P) do { \
  _Pragma("unroll") \
  for (int i_ = 0; i_ < 4; i_++) { \
    a_[i_][0] = *(const short8*)&As[(P)*16384 + (arow0 + i_*16)*64 + kx0]; \
    a_[i_][1] = *(const short8*)&As[(P)*16384 + (arow0 + i_*16)*64 + kx1]; \
    b_[i_][0] = *(const short8*)&Bs[(P)*8192  + (brow0 + i_*16)*64 + kx0]; \
    b_[i_][1] = *(const short8*)&Bs[(P)*8192  + (brow0 + i_*16)*64 + kx1]; \
  } } while(0)

#define MMH(J0) do { \
  __builtin_amdgcn_s_setprio(1); \
  _Pragma("unroll") \
  for (int i_ = 0; i_ < 4; i_++) \
    _Pragma("unroll") \
    for (int j_ = 0; j_ < 2; j_++) { \
      acc[i_][(J0)+j_] = __builtin_amdgcn_mfma_f32_16x16x32_bf16(a_[i_][0], b_[(J0)+j_][0], acc[i_][(J0)+j_], 0, 0, 0); \
      acc[i_][(J0)+j_] = __builtin_amdgcn_mfma_f32_16x16x32_bf16(a_[i_][1], b_[(J0)+j_][1], acc[i_][(J0)+j_], 0, 0, 0); \
    } \
  __builtin_amdgcn_s_setprio(0); } while(0)

#define STGA(P, KK) do { \
  _Pragma("unroll") \
  for (int u_ = 0; u_ < 4; u_++) \
    stage16(Ax + (size_t)(m0 + u_*64 + srow)*1024 + (KK) + schunk, \
            &As[(P)*16384 + u_*4096 + sdst]); \
} while(0)

#define STGB(P, KK) do { \
  _Pragma("unroll") \
  for (int u_ = 0; u_ < 2; u_++) \
    stage16(Btp + (size_t)(n0 + u_*64 + srow)*1024 + (KK) + schunk, \
            &Bs[(P)*8192 + u_*4096 + sdst]); \
} while(0)

#define WB   do { asm volatile("s_waitcnt lgkmcnt(0)" ::: "memory"); __builtin_amdgcn_s_barrier(); } while(0)
#define WBV  do { asm volatile("s_waitcnt vmcnt(6) lgkmcnt(0)" ::: "memory"); __builtin_amdgcn_s_barrier(); } while(0)

DEV void gemm256x128_mainloop(const u16* __restrict__ Ax, const u16* __restrict__ Btp,
                              int m0, int n0, u16* As, u16* Bs, f32x4 acc[4][4])
{
  const int tid = threadIdx.x;
  const int ln = tid & 63, wid = tid >> 6;
  const int wr = wid >> 1, wc = wid & 1;
  const int qr = ln & 15, g = ln >> 4;
  const int srow = wid*8 + (ln >> 3);
  const int schunk = ((ln & 7) ^ (ln >> 3)) * 8;
  const int sdst = wid * 512;
  const int kx0 = ((g    ) ^ (qr & 7)) * 8;
  const int kx1 = ((4 + g) ^ (qr & 7)) * 8;
  const int arow0 = wr*64 + qr;
  const int brow0 = wc*64 + qr;

  #pragma unroll
  for (int i = 0; i < 4; i++)
    #pragma unroll
    for (int j = 0; j < 4; j++) acc[i][j] = (f32x4){0.f, 0.f, 0.f, 0.f};

  short8 a_[4][2], b_[4][2];

  STGA(0, 0);  STGB(0, 0);
  STGA(1, 64); STGB(1, 64);
  asm volatile("s_waitcnt vmcnt(6)" ::: "memory");
  __builtin_amdgcn_s_barrier();

  for (int t = 0; t < 16; t += 2) {
    RDALL(0);
    WB;
    MMH(0);
    { const int k2 = ((t + 2) & 15) * 64; STGA(0, k2); STGB(0, k2); }
    WBV;
    MMH(2);
    RDALL(1);
    WB;
    MMH(0);
    { const int k3 = ((t + 3) & 15) * 64; STGA(1, k3); STGB(1, k3); }
    WBV;
    MMH(2);
  }
}

// ---------------- QKV projection (256x128; 768 blocks = 3 exact waves) ----------------
__global__ __launch_bounds__(512, 2) void qkv_gemm_kernel(
    const u16* __restrict__ A, const u16* __restrict__ WtAll,
    const float* __restrict__ bq, const float* __restrict__ bk, const float* __restrict__ bv,
    u16* __restrict__ Qo, u16* __restrict__ Ko, u16* __restrict__ Vo)
{
  __shared__ __align__(16) u16 As[32768];
  __shared__ __align__(16) u16 Bs[16384];
  const int ln = threadIdx.x & 63, wid = threadIdx.x >> 6;
  const int wr = wid >> 1, wc = wid & 1;
  const int qr = ln & 15, g = ln >> 4;
  const int wg = (blockIdx.x & 7) * 96 + (blockIdx.x >> 3);
  const int mode = wg >> 8;
  const int rem = wg & 255;
  const int n0 = (rem & 7) * 128;
  const int m0 = (rem >> 3) * 256;
  const u16* Btp = WtAll + (size_t)mode * 1048576;
  const float* bias = (mode == 0) ? bq : (mode == 1) ? bk : bv;
  const float osc = (mode == 0) ? 0.1803368867f : 1.0f;

  f32x4 acc[4][4];
  gemm256x128_mainloop(A, Btp, m0, n0, As, Bs, acc);

  if (mode == 2) {
    #pragma unroll
    for (int i = 0; i < 4; i++) {
      const int mrow = m0 + wr*64 + i*16 + g*4;
      const int b = mrow >> 11, s = mrow & 2047;
      #pragma unroll
      for (int j = 0; j < 4; j++) {
        const int n = n0 + wc*64 + j*16 + qr;
        const float bz = bias[n];
        u16x4 v;
        #pragma unroll
        for (int r = 0; r < 4; r++) v[r] = f2bf(acc[i][j][r] + bz);
        *(u16x4*)&Vo[((size_t)(b*16 + (n >> 6))*64 + (n & 63))*2048 + s] = v;
      }
    }
  } else {
    u16* O = (mode == 0) ? Qo : Ko;
    #pragma unroll
    for (int i = 0; i < 4; i++) {
      const int mrow = m0 + wr*64 + i*16 + g*4;
      const int b = mrow >> 11, s = mrow & 2047;
      #pragma unroll
      for (int j = 0; j < 4; j++) {
        const int n = n0 + wc*64 + j*16 + qr;
        const float bz = bias[n];
        const size_t base = ((size_t)(b*16 + (n >> 6))*2048 + s)*64 + (n & 63);
        #pragma unroll
        for (int r = 0; r < 4; r++) O[base + (size_t)r*64] = f2bf((acc[i][j][r] + bz) * osc);
      }
    }
  }
}

// ---------------- flash attention v13: 32 q/wave, 512 blocks = 2 blocks/CU ----------------
// r16 diagnosis: Occupancy ~20% (2 waves/SIMD) with a long per-iter serial chain
// -> both pipes <40% busy. LDS traffic is now small (24KB/CU-iter), so reverse
// the r8 trade: halve q per wave (2 q-sets), double blocks (512) -> 4 waves/SIMD,
// 2 blocks/CU (LDS 44KB x2 = 88KB), de-correlated barrier drains (m114).
// Register state SHRINKS (o[2][4], ol[2], qa/qb[2]) -> no remat risk.
// Staging, 3-buffer counted-vmcnt rotation, P round-trip unchanged from v12.
__global__ __launch_bounds__(512, 2) void attn_kernel(
    const u16* __restrict__ Q, const u16* __restrict__ K,
    const u16* __restrict__ Vt, u16* __restrict__ cat)
{
  __shared__ __align__(16) u16 Ks[3][2048];
  __shared__ __align__(16) u16 Vs[3][2048];
  __shared__ __align__(16) u16 Pl[10240];
  const int lane = threadIdx.x & 63, w = threadIdx.x >> 6;
  const int bid = blockIdx.x;
  const int logical = (bid & 7) * 64 + (bid >> 3);  // XCD swizzle (512 % 8 == 0)
  const int bh = logical >> 3;                 // b*16 + h
  const int xq = logical & 7;
  const int b = bh >> 4, h = bh & 15;
  const int q0 = xq * 256 + w * 32;            // 32 q-rows per wave (2 q-sets)
  const int qr = lane & 15, g = lane >> 4;
  u16* P0 = &Pl[(w*2 + 0)*640];
  u16* P1 = &Pl[(w*2 + 1)*640];

  const u16* Qb = Q  + (size_t)bh * 131072;
  const u16* Kb = K  + (size_t)bh * 131072;
  const u16* Vb = Vt + (size_t)bh * 131072;

  const int isK = (w < 4);
  const int krow = 8*w + (lane >> 3);
  const size_t ksrc = (size_t)krow*64 + (size_t)(((lane & 7) ^ (lane >> 3)) * 8);
  const int vw = w - 4, vrow = 16*vw + (lane >> 2);
  const size_t vsrc = (size_t)vrow*2048 + (size_t)(((lane & 3) ^ ((lane >> 3) & 3)) * 8);
  const int koff = w*512, voff = vw*512;

  const int kro0 = qr*64        + ((g     ^ (qr & 7)) * 8);
  const int kro1 = qr*64        + (((4+g) ^ (qr & 7)) * 8);
  const int kro2 = (16+qr)*64   + ((g     ^ (qr & 7)) * 8);
  const int kro3 = (16+qr)*64   + (((4+g) ^ (qr & 7)) * 8);
  const int vro  = qr*32        + ((g ^ ((qr >> 1) & 3)) * 8);

  short8 qa[2], qb_[2];
  #pragma unroll
  for (int qs = 0; qs < 2; qs++) {
    qa[qs]  = *(const short8*)&Qb[(size_t)(q0 + qs*16 + qr)*64 + g*8];
    qb_[qs] = *(const short8*)&Qb[(size_t)(q0 + qs*16 + qr)*64 + 32 + g*8];
  }

  const short ONE = (short)0x3F80;
  const short8 ones = {ONE, ONE, ONE, ONE, ONE, ONE, ONE, ONE};

  f32x4 o[2][4];
  #pragma unroll
  for (int qs = 0; qs < 2; qs++)
    #pragma unroll
    for (int d = 0; d < 4; d++) o[qs][d] = (f32x4){0.f,0.f,0.f,0.f};
  f32x4 ol[2] = {{0.f,0.f,0.f,0.f},{0.f,0.f,0.f,0.f}};

  if (isK) {
    stage16(Kb + ksrc,        &Ks[0][koff]);
    stage16(Kb + 2048 + ksrc, &Ks[1][koff]);
  } else {
    stage16(Vb + vsrc,        &Vs[0][voff]);
    stage16(Vb + vsrc + 32,   &Vs[1][voff]);
  }

  const u16 *kc_cur = &Ks[0][0], *kc_nx1 = &Ks[1][0], *kc_stg = &Ks[2][0];
  const u16 *vc_cur = &Vs[0][0], *vc_nx1 = &Vs[1][0], *vc_stg = &Vs[2][0];

  for (int tt = 0; tt < 2048; tt += 32) {
    asm volatile("s_waitcnt vmcnt(1)" ::: "memory");
    __builtin_amdgcn_s_barrier();
    const int tn = (tt + 64) & 2047;
    if (isK) stage16(Kb + (size_t)tn*64 + ksrc, (u16*)kc_stg + koff);
    else     stage16(Vb + vsrc + tn,            (u16*)vc_stg + voff);

    short8 kc0 = *(const short8*)&kc_cur[kro0];
    short8 kc1 = *(const short8*)&kc_cur[kro1];
    short8 kc2 = *(const short8*)&kc_cur[kro2];
    short8 kc3 = *(const short8*)&kc_cur[kro3];
    short8 vv0 = *(const short8*)&vc_cur[0*512 + vro];
    short8 vv1 = *(const short8*)&vc_cur[1*512 + vro];
    short8 vv2 = *(const short8*)&vc_cur[2*512 + vro];
    short8 vv3 = *(const short8*)&vc_cur[3*512 + vro];

    #pragma unroll
    for (int qs = 0; qs < 2; qs++) {
      f32x4 sl = {0.f,0.f,0.f,0.f}, sh = {0.f,0.f,0.f,0.f};
      sl = __builtin_amdgcn_mfma_f32_16x16x32_bf16(kc0, qa[qs],  sl, 0, 0, 0);
      sl = __builtin_amdgcn_mfma_f32_16x16x32_bf16(kc1, qb_[qs], sl, 0, 0, 0);
      sh = __builtin_amdgcn_mfma_f32_16x16x32_bf16(kc2, qa[qs],  sh, 0, 0, 0);
      sh = __builtin_amdgcn_mfma_f32_16x16x32_bf16(kc3, qb_[qs], sh, 0, 0, 0);
      u16x4 lo, hi;
      #pragma unroll
      for (int r = 0; r < 4; r++) {
        lo[r] = f2bf(__builtin_amdgcn_exp2f(sl[r]));
        hi[r] = f2bf(__builtin_amdgcn_exp2f(sh[r]));
      }
      u16* P = (qs & 1) ? P1 : P0;
      *(u16x4*)&P[qr*40 + g*4]      = lo;
      *(u16x4*)&P[qr*40 + 16 + g*4] = hi;
      short8 bp = *(const short8*)&P[qr*40 + g*8];
      ol[qs] = __builtin_amdgcn_mfma_f32_16x16x32_bf16(ones, bp, ol[qs], 0, 0, 0);
      o[qs][0] = __builtin_amdgcn_mfma_f32_16x16x32_bf16(vv0, bp, o[qs][0], 0, 0, 0);
      o[qs][1] = __builtin_amdgcn_mfma_f32_16x16x32_bf16(vv1, bp, o[qs][1], 0, 0, 0);
      o[qs][2] = __builtin_amdgcn_mfma_f32_16x16x32_bf16(vv2, bp, o[qs][2], 0, 0, 0);
      o[qs][3] = __builtin_amdgcn_mfma_f32_16x16x32_bf16(vv3, bp, o[qs][3], 0, 0, 0);
    }
    const u16* t0 = kc_cur; kc_cur = kc_nx1; kc_nx1 = kc_stg; kc_stg = t0;
    const u16* t1 = vc_cur; vc_cur = vc_nx1; vc_nx1 = vc_stg; vc_stg = t1;
  }
  #pragma unroll
  for (int qs = 0; qs < 2; qs++) {
    const float inv = 1.0f / ol[qs][0];
    const size_t base = ((size_t)(b*2048 + q0 + qs*16 + qr))*1024 + h*64;
    #pragma unroll
    for (int d = 0; d < 4; d++) {
      u16x4 v;
      #pragma unroll
      for (int r = 0; r < 4; r++) v[r] = f2bf(o[qs][d][r] * inv);
      *(u16x4*)&cat[base + d*16 + g*4] = v;
    }
  }
}

// ---------------- output projection (256x128; 256 blocks = 1 exact wave) ----------------
__global__ __launch_bounds__(512, 2) void out_gemm_kernel(
    const u16* __restrict__ A, const u16* __restrict__ Btp_,
    const float* __restrict__ bias, float* __restrict__ out)
{
  __shared__ __align__(16) u16 As[32768];
  __shared__ __align__(16) u16 Bs[16384];
  const int ln = threadIdx.x & 63, wid = threadIdx.x >> 6;
  const int wr = wid >> 1, wc = wid & 1;
  const int qr = ln & 15, g = ln >> 4;
  const int wg = (blockIdx.x & 7) * 32 + (blockIdx.x >> 3);
  const int n0 = (wg & 7) * 128;
  const int m0 = (wg >> 3) * 256;

  f32x4 acc[4][4];
  gemm256x128_mainloop(A, Btp_, m0, n0, As, Bs, acc);

  #pragma unroll
  for (int i = 0; i < 4; i++) {
    const int mrow = m0 + wr*64 + i*16 + g*4;
    #pragma unroll
    for (int j = 0; j < 4; j++) {
      const int n = n0 + wc*64 + j*16 + qr;
      const float bz = bias[n];
      #pragma unroll
      for (int r = 0; r < 4; r++) out[(size_t)(mrow + r)*1024 + n] = acc[i][j][r] + bz;
    }
  }
}

extern "C" void kernel_launch(void* const* d_in, const int* in_sizes, int n_in,
                              void* d_out, int out_size, void* d_ws, size_t ws_size,
                              hipStream_t stream) {
  const float* x  = (const float*)d_in[0];
  const float* Wq = (const float*)d_in[1];
  const float* bq = (const float*)d_in[2];
  const float* Wk = (const float*)d_in[3];
  const float* bk = (const float*)d_in[4];
  const float* Wv = (const float*)d_in[5];
  const float* bv = (const float*)d_in[6];
  const float* Wo = (const float*)d_in[7];
  const float* bo = (const float*)d_in[8];
  float* out = (float*)d_out;
  char* ws = (char*)d_ws;

  // workspace layout (bytes): xb 16M (reused as cat) | Wt 6M | Wot 2M | Q 16M | K 16M | Vt 16M
  u16* xb  = (u16*)(ws);
  u16* Wt  = (u16*)(ws + 16777216);
  u16* Wot = (u16*)(ws + 23068672);
  u16* Qb  = (u16*)(ws + 25165824);
  u16* Kb  = (u16*)(ws + 41943040);
  u16* Vt  = (u16*)(ws + 58720256);
  u16* cat = xb;  // xb dead after qkv_gemm; attn writes cat there

  cvt_kernel<<<5120, 256, 0, stream>>>(x, Wq, Wk, Wv, Wo, xb, Wt, Wot);
  qkv_gemm_kernel<<<768, 512, 0, stream>>>(xb, Wt, bq, bk, bv, Qb, Kb, Vt);
  attn_kernel<<<512, 512, 0, stream>>>(Qb, Kb, Vt, cat);
  out_gemm_kernel<<<256, 512, 0, stream>>>(cat, Wot, bo, out);
}

// Round 18
// 177.350 us; speedup vs baseline: 1.0146x; 1.0146x over previous
//
#include <hip/hip_runtime.h>
#include <hip/hip_bf16.h>
#include <stdint.h>

typedef unsigned short u16;
typedef __attribute__((ext_vector_type(8))) short short8;   // 8 bf16 (4 VGPRs) MFMA A/B frag
typedef __attribute__((ext_vector_type(4))) float f32x4;    // MFMA C/D frag
typedef __attribute__((ext_vector_type(4))) unsigned short u16x4;

#define DEV static __device__ __forceinline__

// B=4, S=2048, D=1024, H=16, DK=64, DOUT=1024; M = B*S = 8192

DEV u16 f2bf(float f) {
  __hip_bfloat16 b = __float2bfloat16(f);
  return *(u16*)&b;
}

DEV void stage16(const u16* g, u16* l) {
  // async global->LDS, 16B per lane; LDS dest = wave-uniform base + lane*16
  __builtin_amdgcn_global_load_lds((const __attribute__((address_space(1))) void*)g,
                                   (__attribute__((address_space(3))) void*)l, 16, 0, 0);
}

// ---------------- conversions + LDS-mediated weight transposes ----------------
__global__ __launch_bounds__(256) void cvt_kernel(
    const float* __restrict__ x, const float* __restrict__ Wq,
    const float* __restrict__ Wk, const float* __restrict__ Wv,
    const float* __restrict__ Wo,
    u16* __restrict__ xb, u16* __restrict__ Wt, u16* __restrict__ Wot)
{
  const int bid = blockIdx.x, tid = threadIdx.x;
  if (bid < 4096) {                       // x: [8192][1024] f32 -> bf16, 8/thread
    int i = (bid*256 + tid) * 8;
    f32x4 v0 = *(const f32x4*)&x[i];
    f32x4 v1 = *(const f32x4*)&x[i + 4];
    short8 o;
    o[0]=f2bf(v0[0]); o[1]=f2bf(v0[1]); o[2]=f2bf(v0[2]); o[3]=f2bf(v0[3]);
    o[4]=f2bf(v1[0]); o[5]=f2bf(v1[1]); o[6]=f2bf(v1[2]); o[7]=f2bf(v1[3]);
    *(short8*)&xb[i] = o;
    return;
  }
  __shared__ u16 ldsT[64][72];            // padded: write-phase rows 16B-aligned
  const float* sp; size_t sstride; u16* dp;
  if (bid < 4864) {                       // Wq/Wk/Wv [H][D][DK] -> Wt[w][h*64+k][d]
    const int wb = bid - 4096;            // 768 blocks: (w, h, dblk)
    const int w = wb >> 8, rem = wb & 255;
    const int h = rem >> 4, db = rem & 15;
    const float* W = (w == 0) ? Wq : (w == 1) ? Wk : Wv;
    sp = W + (size_t)(h*1024 + db*64) * 64;
    sstride = 64;
    dp = Wt + (size_t)w*1048576 + (size_t)(h*64)*1024 + db*64;
  } else {                                // Wo [f][n] -> Wot[n][f]
    const int ob = bid - 4864;            // 256 blocks: (nb, fb)
    const int nb = ob >> 4, fb = ob & 15;
    sp = Wo + (size_t)(fb*64)*1024 + nb*64;
    sstride = 1024;
    dp = Wot + (size_t)(nb*64)*1024 + fb*64;
  }
  {   // coalesced read: 4 threads/row, 16 f32 each; scatter bf16 into ldsT[col][row]
    const int r = tid >> 2, c0 = (tid & 3) * 16;
    #pragma unroll
    for (int j = 0; j < 4; j++) {
      f32x4 v = *(const f32x4*)&sp[(size_t)r*sstride + c0 + j*4];
      #pragma unroll
      for (int i = 0; i < 4; i++) ldsT[c0 + j*4 + i][r] = f2bf(v[i]);
    }
  }
  __syncthreads();
  {   // coalesced write: 4 threads/row, 2x16B each
    const int k = tid >> 2, d0 = (tid & 3) * 16;
    short8 v0 = *(const short8*)&ldsT[k][d0];
    short8 v1 = *(const short8*)&ldsT[k][d0 + 8];
    *(short8*)&dp[(size_t)k*1024 + d0]     = v0;
    *(short8*)&dp[(size_t)k*1024 + d0 + 8] = v1;
  }
}

// ============ 256x128 2-phase-per-tile GEMM mainloop (BK=64, 8 waves 4Mx2N) ============
#define RDALL(P) do { \
  _Pragma("unroll") \
  for (int i_ = 0; i_ < 4; i_++) { \
    a_[i_][0] = *(const short8*)&As[(P)*16384 + (arow0 + i_*16)*64 + kx0]; \
    a_[i_][1] = *(const short8*)&As[(P)*16384 + (arow0 + i_*16)*64 + kx1]; \
    b_[i_][0] = *(const short8*)&Bs[(P)*8192  + (brow0 + i_*16)*64 + kx0]; \
    b_[i_][1] = *(const short8*)&Bs[(P)*8192  + (brow0 + i_*16)*64 + kx1]; \
  } } while(0)

#define MMH(J0) do { \
  __builtin_amdgcn_s_setprio(1); \
  _Pragma("unroll") \
  for (int i_ = 0; i_ < 4; i_++) \
    _Pragma("unroll") \
    for (int j_ = 0; j_ < 2; j_++) { \
      acc[i_][(J0)+j_] = __builtin_amdgcn_mfma_f32_16x16x32_bf16(a_[i_][0], b_[(J0)+j_][0], acc[i_][(J0)+j_], 0, 0, 0); \
      acc[i_][(J0)+j_] = __builtin_amdgcn_mfma_f32_16x16x32_bf16(a_[i_][1], b_[(J0)+j_][1], acc[i_][(J0)+j_], 0, 0, 0); \
    } \
  __builtin_amdgcn_s_setprio(0); } while(0)

#define STGA(P, KK) do { \
  _Pragma("unroll") \
  for (int u_ = 0; u_ < 4; u_++) \
    stage16(Ax + (size_t)(m0 + u_*64 + srow)*1024 + (KK) + schunk, \
            &As[(P)*16384 + u_*4096 + sdst]); \
} while(0)

#define STGB(P, KK) do { \
  _Pragma("unroll") \
  for (int u_ = 0; u_ < 2; u_++) \
    stage16(Btp + (size_t)(n0 + u_*64 + srow)*1024 + (KK) + schunk, \
            &Bs[(P)*8192 + u_*4096 + sdst]); \
} while(0)

#define WB   do { asm volatile("s_waitcnt lgkmcnt(0)" ::: "memory"); __builtin_amdgcn_s_barrier(); } while(0)
#define WBV  do { asm volatile("s_waitcnt vmcnt(6) lgkmcnt(0)" ::: "memory"); __builtin_amdgcn_s_barrier(); } while(0)

DEV void gemm256x128_mainloop(const u16* __restrict__ Ax, const u16* __restrict__ Btp,
                              int m0, int n0, u16* As, u16* Bs, f32x4 acc[4][4])
{
  const int tid = threadIdx.x;
  const int ln = tid & 63, wid = tid >> 6;
  const int wr = wid >> 1, wc = wid & 1;
  const int qr = ln & 15, g = ln >> 4;
  const int srow = wid*8 + (ln >> 3);
  const int schunk = ((ln & 7) ^ (ln >> 3)) * 8;
  const int sdst = wid * 512;
  const int kx0 = ((g    ) ^ (qr & 7)) * 8;
  const int kx1 = ((4 + g) ^ (qr & 7)) * 8;
  const int arow0 = wr*64 + qr;
  const int brow0 = wc*64 + qr;

  #pragma unroll
  for (int i = 0; i < 4; i++)
    #pragma unroll
    for (int j = 0; j < 4; j++) acc[i][j] = (f32x4){0.f, 0.f, 0.f, 0.f};

  short8 a_[4][2], b_[4][2];

  STGA(0, 0);  STGB(0, 0);
  STGA(1, 64); STGB(1, 64);
  asm volatile("s_waitcnt vmcnt(6)" ::: "memory");
  __builtin_amdgcn_s_barrier();

  for (int t = 0; t < 16; t += 2) {
    RDALL(0);
    WB;
    MMH(0);
    { const int k2 = ((t + 2) & 15) * 64; STGA(0, k2); STGB(0, k2); }
    WBV;
    MMH(2);
    RDALL(1);
    WB;
    MMH(0);
    { const int k3 = ((t + 3) & 15) * 64; STGA(1, k3); STGB(1, k3); }
    WBV;
    MMH(2);
  }
}

// ---------------- QKV projection (256x128; 768 blocks = 3 exact waves) ----------------
// Q/K epilogue now bounces the 256x128 bf16 tile through LDS (reusing As, dead
// after mainloop; vmcnt(0)+barrier first since late prefetches still target it)
// -> stores become 8 coalesced short8/thread instead of scalar u16 at 512B
// strides (partial-line writes on 16MB of Q+K). V path already vectorized.
__global__ __launch_bounds__(512, 2) void qkv_gemm_kernel(
    const u16* __restrict__ A, const u16* __restrict__ WtAll,
    const float* __restrict__ bq, const float* __restrict__ bk, const float* __restrict__ bv,
    u16* __restrict__ Qo, u16* __restrict__ Ko, u16* __restrict__ Vo)
{
  __shared__ __align__(16) u16 As[32768];
  __shared__ __align__(16) u16 Bs[16384];
  const int ln = threadIdx.x & 63, wid = threadIdx.x >> 6;
  const int wr = wid >> 1, wc = wid & 1;
  const int qr = ln & 15, g = ln >> 4;
  const int wg = (blockIdx.x & 7) * 96 + (blockIdx.x >> 3);
  const int mode = wg >> 8;
  const int rem = wg & 255;
  const int n0 = (rem & 7) * 128;
  const int m0 = (rem >> 3) * 256;
  const u16* Btp = WtAll + (size_t)mode * 1048576;
  const float* bias = (mode == 0) ? bq : (mode == 1) ? bk : bv;
  const float osc = (mode == 0) ? 0.1803368867f : 1.0f;

  f32x4 acc[4][4];
  gemm256x128_mainloop(A, Btp, m0, n0, As, Bs, acc);

  if (mode == 2) {
    #pragma unroll
    for (int i = 0; i < 4; i++) {
      const int mrow = m0 + wr*64 + i*16 + g*4;
      const int b = mrow >> 11, s = mrow & 2047;
      #pragma unroll
      for (int j = 0; j < 4; j++) {
        const int n = n0 + wc*64 + j*16 + qr;
        const float bz = bias[n];
        u16x4 v;
        #pragma unroll
        for (int r = 0; r < 4; r++) v[r] = f2bf(acc[i][j][r] + bz);
        *(u16x4*)&Vo[((size_t)(b*16 + (n >> 6))*64 + (n & 63))*2048 + s] = v;
      }
    }
  } else {
    u16* O = (mode == 0) ? Qo : Ko;         // [b][h][s][dk]
    // drain in-flight prefetches targeting As, then reuse As as bounce buffer
    asm volatile("s_waitcnt vmcnt(0)" ::: "memory");
    __syncthreads();
    #pragma unroll
    for (int i = 0; i < 4; i++) {
      #pragma unroll
      for (int j = 0; j < 4; j++) {
        const int nLoc = wc*64 + j*16 + qr;
        const float bz = bias[n0 + nLoc];
        #pragma unroll
        for (int r = 0; r < 4; r++) {
          const int sLoc = wr*64 + i*16 + g*4 + r;
          As[sLoc*128 + nLoc] = f2bf((acc[i][j][r] + bz) * osc);
        }
      }
    }
    __syncthreads();
    const int b = m0 >> 11, sBase = m0 & 2047, h0 = n0 >> 6;
    #pragma unroll
    for (int it = 0; it < 8; it++) {
      const int idx = it*512 + threadIdx.x;
      const int sLoc = idx >> 4, ch = idx & 15;
      short8 v = *(const short8*)&As[sLoc*128 + ch*8];
      *(short8*)&O[((size_t)(b*16 + h0 + (ch >> 3))*2048 + sBase + sLoc)*64 + (ch & 7)*8] = v;
    }
  }
}

// ---------------- flash attention v12 (r16 config: 64q/wave, 256 blocks; 81.7us) ----------------
__global__ __launch_bounds__(512, 2) void attn_kernel(
    const u16* __restrict__ Q, const u16* __restrict__ K,
    const u16* __restrict__ Vt, u16* __restrict__ cat)
{
  __shared__ __align__(16) u16 Ks[3][2048];
  __shared__ __align__(16) u16 Vs[3][2048];
  __shared__ __align__(16) u16 Pl[10240];
  const int lane = threadIdx.x & 63, w = threadIdx.x >> 6;
  const int bid = blockIdx.x;
  const int logical = (bid & 7) * 32 + (bid >> 3);
  const int bh = logical >> 2;
  const int xq = logical & 3;
  const int b = bh >> 4, h = bh & 15;
  const int q0 = xq * 512 + w * 64;
  const int qr = lane & 15, g = lane >> 4;
  u16* P0 = &Pl[(w*2 + 0)*640];
  u16* P1 = &Pl[(w*2 + 1)*640];

  const u16* Qb = Q  + (size_t)bh * 131072;
  const u16* Kb = K  + (size_t)bh * 131072;
  const u16* Vb = Vt + (size_t)bh * 131072;

  const int isK = (w < 4);
  const int krow = 8*w + (lane >> 3);
  const size_t ksrc = (size_t)krow*64 + (size_t)(((lane & 7) ^ (lane >> 3)) * 8);
  const int vw = w - 4, vrow = 16*vw + (lane >> 2);
  const size_t vsrc = (size_t)vrow*2048 + (size_t)(((lane & 3) ^ ((lane >> 3) & 3)) * 8);
  const int koff = w*512, voff = vw*512;

  const int kro0 = qr*64        + ((g     ^ (qr & 7)) * 8);
  const int kro1 = qr*64        + (((4+g) ^ (qr & 7)) * 8);
  const int kro2 = (16+qr)*64   + ((g     ^ (qr & 7)) * 8);
  const int kro3 = (16+qr)*64   + (((4+g) ^ (qr & 7)) * 8);
  const int vro  = qr*32        + ((g ^ ((qr >> 1) & 3)) * 8);

  short8 qa[4], qb_[4];
  #pragma unroll
  for (int qs = 0; qs < 4; qs++) {
    qa[qs]  = *(const short8*)&Qb[(size_t)(q0 + qs*16 + qr)*64 + g*8];
    qb_[qs] = *(const short8*)&Qb[(size_t)(q0 + qs*16 + qr)*64 + 32 + g*8];
  }

  const short ONE = (short)0x3F80;
  const short8 ones = {ONE, ONE, ONE, ONE, ONE, ONE, ONE, ONE};

  f32x4 o[4][4];
  #pragma unroll
  for (int qs = 0; qs < 4; qs++)
    #pragma unroll
    for (int d = 0; d < 4; d++) o[qs][d] = (f32x4){0.f,0.f,0.f,0.f};
  f32x4 ol[4] = {{0.f,0.f,0.f,0.f},{0.f,0.f,0.f,0.f},{0.f,0.f,0.f,0.f},{0.f,0.f,0.f,0.f}};

  if (isK) {
    stage16(Kb + ksrc,        &Ks[0][koff]);
    stage16(Kb + 2048 + ksrc, &Ks[1][koff]);
  } else {
    stage16(Vb + vsrc,        &Vs[0][voff]);
    stage16(Vb + vsrc + 32,   &Vs[1][voff]);
  }

  const u16 *kc_cur = &Ks[0][0], *kc_nx1 = &Ks[1][0], *kc_stg = &Ks[2][0];
  const u16 *vc_cur = &Vs[0][0], *vc_nx1 = &Vs[1][0], *vc_stg = &Vs[2][0];

  for (int tt = 0; tt < 2048; tt += 32) {
    asm volatile("s_waitcnt vmcnt(1)" ::: "memory");
    __builtin_amdgcn_s_barrier();
    const int tn = (tt + 64) & 2047;
    if (isK) stage16(Kb + (size_t)tn*64 + ksrc, (u16*)kc_stg + koff);
    else     stage16(Vb + vsrc + tn,            (u16*)vc_stg + voff);

    short8 kc0 = *(const short8*)&kc_cur[kro0];
    short8 kc1 = *(const short8*)&kc_cur[kro1];
    short8 kc2 = *(const short8*)&kc_cur[kro2];
    short8 kc3 = *(const short8*)&kc_cur[kro3];
    short8 vv0 = *(const short8*)&vc_cur[0*512 + vro];
    short8 vv1 = *(const short8*)&vc_cur[1*512 + vro];
    short8 vv2 = *(const short8*)&vc_cur[2*512 + vro];
    short8 vv3 = *(const short8*)&vc_cur[3*512 + vro];

    #pragma unroll
    for (int qs = 0; qs < 4; qs++) {
      f32x4 sl = {0.f,0.f,0.f,0.f}, sh = {0.f,0.f,0.f,0.f};
      sl = __builtin_amdgcn_mfma_f32_16x16x32_bf16(kc0, qa[qs],  sl, 0, 0, 0);
      sl = __builtin_amdgcn_mfma_f32_16x16x32_bf16(kc1, qb_[qs], sl, 0, 0, 0);
      sh = __builtin_amdgcn_mfma_f32_16x16x32_bf16(kc2, qa[qs],  sh, 0, 0, 0);
      sh = __builtin_amdgcn_mfma_f32_16x16x32_bf16(kc3, qb_[qs], sh, 0, 0, 0);
      u16x4 lo, hi;
      #pragma unroll
      for (int r = 0; r < 4; r++) {
        lo[r] = f2bf(__builtin_amdgcn_exp2f(sl[r]));
        hi[r] = f2bf(__builtin_amdgcn_exp2f(sh[r]));
      }
      u16* P = (qs & 1) ? P1 : P0;
      *(u16x4*)&P[qr*40 + g*4]      = lo;
      *(u16x4*)&P[qr*40 + 16 + g*4] = hi;
      short8 bp = *(const short8*)&P[qr*40 + g*8];
      ol[qs] = __builtin_amdgcn_mfma_f32_16x16x32_bf16(ones, bp, ol[qs], 0, 0, 0);
      o[qs][0] = __builtin_amdgcn_mfma_f32_16x16x32_bf16(vv0, bp, o[qs][0], 0, 0, 0);
      o[qs][1] = __builtin_amdgcn_mfma_f32_16x16x32_bf16(vv1, bp, o[qs][1], 0, 0, 0);
      o[qs][2] = __builtin_amdgcn_mfma_f32_16x16x32_bf16(vv2, bp, o[qs][2], 0, 0, 0);
      o[qs][3] = __builtin_amdgcn_mfma_f32_16x16x32_bf16(vv3, bp, o[qs][3], 0, 0, 0);
    }
    const u16* t0 = kc_cur; kc_cur = kc_nx1; kc_nx1 = kc_stg; kc_stg = t0;
    const u16* t1 = vc_cur; vc_cur = vc_nx1; vc_nx1 = vc_stg; vc_stg = t1;
  }
  #pragma unroll
  for (int qs = 0; qs < 4; qs++) {
    const float inv = 1.0f / ol[qs][0];
    const size_t base = ((size_t)(b*2048 + q0 + qs*16 + qr))*1024 + h*64;
    #pragma unroll
    for (int d = 0; d < 4; d++) {
      u16x4 v;
      #pragma unroll
      for (int r = 0; r < 4; r++) v[r] = f2bf(o[qs][d][r] * inv);
      *(u16x4*)&cat[base + d*16 + g*4] = v;
    }
  }
}

// ---------------- output projection (256x128; 256 blocks = 1 exact wave) ----------------
__global__ __launch_bounds__(512, 2) void out_gemm_kernel(
    const u16* __restrict__ A, const u16* __restrict__ Btp_,
    const float* __restrict__ bias, float* __restrict__ out)
{
  __shared__ __align__(16) u16 As[32768];
  __shared__ __align__(16) u16 Bs[16384];
  const int ln = threadIdx.x & 63, wid = threadIdx.x >> 6;
  const int wr = wid >> 1, wc = wid & 1;
  const int qr = ln & 15, g = ln >> 4;
  const int wg = (blockIdx.x & 7) * 32 + (blockIdx.x >> 3);
  const int n0 = (wg & 7) * 128;
  const int m0 = (wg >> 3) * 256;

  f32x4 acc[4][4];
  gemm256x128_mainloop(A, Btp_, m0, n0, As, Bs, acc);

  #pragma unroll
  for (int i = 0; i < 4; i++) {
    const int mrow = m0 + wr*64 + i*16 + g*4;
    #pragma unroll
    for (int j = 0; j < 4; j++) {
      const int n = n0 + wc*64 + j*16 + qr;
      const float bz = bias[n];
      #pragma unroll
      for (int r = 0; r < 4; r++) out[(size_t)(mrow + r)*1024 + n] = acc[i][j][r] + bz;
    }
  }
}

extern "C" void kernel_launch(void* const* d_in, const int* in_sizes, int n_in,
                              void* d_out, int out_size, void* d_ws, size_t ws_size,
                              hipStream_t stream) {
  const float* x  = (const float*)d_in[0];
  const float* Wq = (const float*)d_in[1];
  const float* bq = (const float*)d_in[2];
  const float* Wk = (const float*)d_in[3];
  const float* bk = (const float*)d_in[4];
  const float* Wv = (const float*)d_in[5];
  const float* bv = (const float*)d_in[6];
  const float* Wo = (const float*)d_in[7];
  const float* bo = (const float*)d_in[8];
  float* out = (float*)d_out;
  char* ws = (char*)d_ws;

  // workspace layout (bytes): xb 16M (reused as cat) | Wt 6M | Wot 2M | Q 16M | K 16M | Vt 16M
  u16* xb  = (u16*)(ws);
  u16* Wt  = (u16*)(ws + 16777216);
  u16* Wot = (u16*)(ws + 23068672);
  u16* Qb  = (u16*)(ws + 25165824);
  u16* Kb  = (u16*)(ws + 41943040);
  u16* Vt  = (u16*)(ws + 58720256);
  u16* cat = xb;  // xb dead after qkv_gemm; attn writes cat there

  cvt_kernel<<<5120, 256, 0, stream>>>(x, Wq, Wk, Wv, Wo, xb, Wt, Wot);
  qkv_gemm_kernel<<<768, 512, 0, stream>>>(xb, Wt, bq, bk, bv, Qb, Kb, Vt);
  attn_kernel<<<256, 512, 0, stream>>>(Qb, Kb, Vt, cat);
  out_gemm_kernel<<<256, 512, 0, stream>>>(cat, Wot, bo, out);
}